// Round 13
// baseline (291.608 us; speedup 1.0000x reference)
//
#include <hip/hip_runtime.h>
#include <stdint.h>

#define BB 128
#define TT 3000
#define CC 64
#define LL 128
// S = 2L+1 = 257 ; states 0..255 live on 4 waves x 64 lanes; state 256 via tail pass
#define NEGf (-1e30f)
#define LOG2E 1.4426950408889634f
#define LN2f 0.6931471805599453f
#define F 12                  // frames per ring chunk; 3000 = 250 * 12
#define NCH 250
#define NBUF 5                // ring depth: producers at c+1, wave3 at c-3
#define NPH (NCH + 3)
#define LSE_BLOCKS 512

typedef float f32x2 __attribute__((ext_vector_type(2)));

__device__ __forceinline__ float fexp2(float x){ return __builtin_amdgcn_exp2f(x); }
__device__ __forceinline__ float flog2(float x){ return __builtin_amdgcn_logf(x); }
// lane l <- lane l-1 (lane 0 -> NEG) via DPP wave_shr:1
__device__ __forceinline__ float shr1_neg(float x){
    int r = __builtin_amdgcn_update_dpp(__float_as_int(NEGf), __float_as_int(x),
                                        0x138, 0xF, 0xF, false);
    return __int_as_float(r);
}
#define DPPMAXT(x,c) fmaxf((x),__int_as_float(__builtin_amdgcn_update_dpp(0,__float_as_int(x),(c),0xF,0xF,true)))
#define DPPADDT(x,c) ((x)+__int_as_float(__builtin_amdgcn_update_dpp(0,__float_as_int(x),(c),0xF,0xF,true)))
#define RED64(OP,x) { x=OP(x,0x111); x=OP(x,0x112); x=OP(x,0x114); x=OP(x,0x118); x=OP(x,0x142); x=OP(x,0x143); }

// Fused kernel, 512 threads/block.
// Scan blocks (blockIdx < BB): waves 0-3 = consumers (1 CTC state per lane,
// log-domain lse3 via sorted-2-exp + deg-5 poly-log; wave w lags w chunks;
// boundary = lane63 alpha through mod-3 LDS slot rings). Waves 4-7 = producers
// (gather target/blank logits, scale by LOG2E, stage log-domain em ring).
// State 256 reconstructed post-loop from logged la255(t) + blank prefix sums.
__global__ __launch_bounds__(512) void fused_kernel(const float* __restrict__ in,
                                                    const int* __restrict__ tgt,
                                                    float* __restrict__ lse,
                                                    float* __restrict__ ll2){
    __shared__ float emR[NBUF][F][132];  // per frame: [0..127]=em(target i), [128]=em blank
    __shared__ float bndR[5][3][F];      // region w read by wave w; written by wave w-1
    __shared__ float laL[3008];          // la255(t) log (wave3 lane63)
    __shared__ float lbL[3008];          // lemB(t) log (producers)
    __shared__ float dmp[64];
    if (blockIdx.x < BB) {
        const int b = blockIdx.x;
        const int wave = threadIdx.x >> 6;
        const int lane = threadIdx.x & 63;
        const float* fb = in + (size_t)b * TT * CC;
        const uint32_t em_base  = (uint32_t)(uintptr_t)&emR[0][0][0];
        const uint32_t bnd_base = (uint32_t)(uintptr_t)&bndR[0][0][0];
        const uint32_t la_base  = (uint32_t)(uintptr_t)&laL[0];
        const uint32_t dmp_base = (uint32_t)(uintptr_t)&dmp[0];

        if (wave < 4) {
            const int w = wave;
            __builtin_amdgcn_s_setprio(1);
            if (w == 0) {
                float* bp = &bndR[0][0][0];
                if (lane < 3*F) bp[lane] = NEGf;          // region 0 = NEG constant
                if (lane < 3) bndR[lane+1][0][0] = NEGf;  // a(-1) for chunk-0 step-0
                if (lane < 8) { laL[3000+lane] = NEGf; lbL[3000+lane] = 0.f; }
            }
            const bool odd = (lane & 1);
            const uint32_t em_off = odd ? (uint32_t)(32*w + (lane>>1))*4u : 512u;
            float aa = (w==0 && lane==0) ? 0.f : NEGf;   // virtual pre-t=0 state
            __syncthreads();
            for (int ph = 0; ph < NPH; ++ph) {
                const int x = ph - w;
                if (x >= 0 && x < NCH) {
                    const uint32_t buf = (uint32_t)(x % NBUF);
                    const uint32_t ra  = em_base + buf*(F*132u*4u) + em_off;
                    const uint32_t xm3 = (uint32_t)(x % 3);
                    const uint32_t xp3 = (uint32_t)((x+1) % 3);
                    const uint32_t rb  = bnd_base + (uint32_t)w*144u + xm3*48u;
                    const uint32_t wbm = (lane==63) ? (bnd_base + (uint32_t)(w+1)*144u + xm3*48u)
                                                    : (dmp_base + (uint32_t)lane*4u);
                    const uint32_t wbl = (lane==63) ? (bnd_base + (uint32_t)(w+1)*144u + xp3*48u)
                                                    : (dmp_base + (uint32_t)lane*4u);
                    const uint32_t wl  = (w==3 && lane==63) ? (la_base + (uint32_t)(x*F)*4u)
                                                            : (dmp_base + (uint32_t)lane*4u);
                    float e0,e1,e2,b0,b1,b2;
                    asm volatile("ds_read_b32 %0, %1 offset:0"   : "=v"(e0) : "v"(ra));
                    asm volatile("ds_read_b32 %0, %1 offset:0"   : "=v"(b0) : "v"(rb));
                    asm volatile("ds_read_b32 %0, %1 offset:528" : "=v"(e1) : "v"(ra));
                    asm volatile("ds_read_b32 %0, %1 offset:4"   : "=v"(b1) : "v"(rb));
                    #pragma unroll
                    for (int j = 0; j < F; ++j) {
                        const int jn = (j+2 < F) ? (j+2) : (F-1);
                        asm volatile("ds_read_b32 %0, %1 offset:%2" : "=v"(e2) : "v"(ra), "n"(jn*528));
                        asm volatile("ds_read_b32 %0, %1 offset:%2" : "=v"(b2) : "v"(rb), "n"(jn*4));
                        if (j == 0)      asm volatile("s_waitcnt lgkmcnt(4)" ::: "memory");
                        else if (j == 1) asm volatile("s_waitcnt lgkmcnt(6)" ::: "memory");
                        else             asm volatile("s_waitcnt lgkmcnt(8)" ::: "memory");
                        __builtin_amdgcn_sched_barrier(0);   // rule #18
                        float p1 = shr1_neg(aa);             // a_{s-1}(t-1)
                        float p2 = shr1_neg(p1);             // a_{s-2}(t-1)
                        p1 = (lane==0) ? b0 : p1;            // cross-wave boundary
                        p2 = (lane==1) ? b0 : p2;
                        float z = odd ? p2 : NEGf;           // skip only for odd states
                        // lse3(aa,p1,z) via sort + 2 exp + poly log2(1+e), e in [0,2]
                        float mx = fmaxf(fmaxf(aa,p1),z);
                        float md = __builtin_amdgcn_fmed3f(aa,p1,z);
                        float mn = fminf(fminf(aa,p1),z);
                        float e  = fexp2(md-mx) + fexp2(mn-mx);
                        float v  = __builtin_fmaf(e,0.5f,-0.5f);      // (e-1)/2 in [-.5,.5]
                        float h  = __builtin_fmaf(v,0.2f,-0.25f);     // deg-5 ln(1+v) series
                        h = __builtin_fmaf(v,h,0.33333333f);
                        h = __builtin_fmaf(v,h,-0.5f);
                        h = __builtin_fmaf(v,h,1.0f);
                        aa = __builtin_fmaf(v*h, LOG2E, mx+1.0f) + e0;  // + em (log2 domain)
                        if (j < F-1) { asm volatile("ds_write_b32 %0, %1 offset:%2" :: "v"(wbm), "v"(aa), "n"((j+1)*4)); }
                        else         { asm volatile("ds_write_b32 %0, %1 offset:0"  :: "v"(wbl), "v"(aa)); }
                        asm volatile("ds_write_b32 %0, %1 offset:%2" :: "v"(wl), "v"(aa), "n"(j*4));
                        e0=e1; b0=b1; e1=e2; b1=b2;
                    }
                    asm volatile("s_waitcnt lgkmcnt(0)" ::: "memory");  // drain before barrier
                }
                __syncthreads();
            }
            __syncthreads();   // tail barrier (all waves)
            if (w == 0) {
                // la256(T-1) = lse_{tau<=T-2}( la255(tau) + CBtot - CB(tau) )
                const int base = lane*47;               // 3008 = 64*47
                float seg = 0.f;
                for (int k = 0; k < 47; ++k) seg += lbL[base+k];
                float inc = seg;
                #pragma unroll
                for (int d = 1; d < 64; d <<= 1) {
                    float t = __shfl_up(inc, d, 64);
                    if (lane >= d) inc += t;
                }
                float CBtot = __int_as_float(__builtin_amdgcn_readlane(__float_as_int(inc), 63));
                float ex = inc - seg;
                float cb = ex, gm = NEGf;
                for (int k = 0; k < 47; ++k) {
                    int idx = base+k;
                    cb += lbL[idx];
                    float g = laL[idx] + (CBtot - cb);
                    g = (idx == 2999) ? NEGf : g;
                    gm = fmaxf(gm, g);
                }
                RED64(DPPMAXT, gm);
                float gmax = __int_as_float(__builtin_amdgcn_readlane(__float_as_int(gm), 63));
                cb = ex; float se = 0.f;
                for (int k = 0; k < 47; ++k) {
                    int idx = base+k;
                    cb += lbL[idx];
                    float g = laL[idx] + (CBtot - cb);
                    g = (idx == 2999) ? NEGf : g;
                    se += fexp2(g - gmax);
                }
                RED64(DPPADDT, se);
                float S = __int_as_float(__builtin_amdgcn_readlane(__float_as_int(se), 63));
                float la256 = gmax + flog2(S);
                float la255f = laL[2999];
                float m = fmaxf(la255f, la256);
                float r = m + flog2(1.0f + fexp2(-fabsf(la255f - la256)));
                if (lane == 0) ll2[b] = r;
            }
        } else {
            // producers: wave p handles frames 3p..3p+2 of each chunk
            const int p = wave - 4;
            const int t0 = tgt[b*LL + 2*lane];       // channel for em slot 2*lane   (state 4l+1... slot i <-> state 2i+1)
            const int t1 = tgt[b*LL + 2*lane + 1];   // channel for em slot 2*lane+1
            auto produce = [&](int cc) {
                const int buf = cc % NBUF;
                const float* cbase = fb + (size_t)cc * F * CC;
                float v0[3], v1[3], vb[3];
                #pragma unroll
                for (int k = 0; k < 3; ++k) {
                    const float* fr = cbase + (3*p + k)*CC;
                    v0[k] = fr[t0]; v1[k] = fr[t1]; vb[k] = fr[63];
                }
                #pragma unroll
                for (int k = 0; k < 3; ++k) {
                    const int f = 3*p + k;
                    f32x2 wv; wv.x = v0[k]*LOG2E; wv.y = v1[k]*LOG2E;
                    *(f32x2*)&emR[buf][f][2*lane] = wv;
                    if (lane == 0) {
                        float xb = vb[k]*LOG2E;
                        emR[buf][f][128] = xb;
                        lbL[cc*F + f] = xb;
                    }
                }
            };
            produce(0);
            __syncthreads();
            for (int ph = 0; ph < NPH; ++ph) {
                if (ph + 1 < NCH) produce(ph + 1);
                __syncthreads();
            }
            __syncthreads();   // tail barrier
        }
        return;
    }
    // ---- softmax normalizer: one wave per (b,t) row, grid-strided ----
    int wv = (blockIdx.x - BB) * 8 + (threadIdx.x >> 6);
    int lane = threadIdx.x & 63;
    const int stride = LSE_BLOCKS * 8;
    for (int row = wv; row < BB * TT; row += stride) {
        float x = in[(size_t)row * CC + lane];
        float m = x;
        #pragma unroll
        for (int d = 32; d >= 1; d >>= 1) m = fmaxf(m, __shfl_xor(m, d, 64));
        float s = fexp2((x - m) * LOG2E);
        #pragma unroll
        for (int d = 32; d >= 1; d >>= 1) s += __shfl_xor(s, d, 64);
        if (lane == 0) lse[row] = m + flog2(s) * LN2f;
    }
}

// per-batch loss_b = sum_t lse_nat[b,t] - ll2[b]*ln2
__global__ __launch_bounds__(256) void bsum_kernel(const float* __restrict__ lse,
                                                   const float* __restrict__ ll2,
                                                   float* __restrict__ lossb) {
    __shared__ float red[256];
    int b = blockIdx.x;
    float s = 0.f;
    for (int i = threadIdx.x; i < TT; i += 256) s += lse[(size_t)b * TT + i];
    red[threadIdx.x] = s;
    __syncthreads();
    #pragma unroll
    for (int w = 128; w >= 1; w >>= 1) {
        if (threadIdx.x < w) red[threadIdx.x] += red[threadIdx.x + w];
        __syncthreads();
    }
    if (threadIdx.x == 0) lossb[b] = red[0] - ll2[b] * LN2f;
}

// mean over batch
__global__ __launch_bounds__(64) void final_kernel(const float* __restrict__ lossb,
                                                   float* __restrict__ out) {
    int lane = threadIdx.x;
    float v = lossb[lane] + lossb[lane + 64];
    #pragma unroll
    for (int d = 32; d >= 1; d >>= 1) v += __shfl_xor(v, d, 64);
    if (lane == 0) out[0] = v / (float)BB;
}

extern "C" void kernel_launch(void* const* d_in, const int* in_sizes, int n_in,
                              void* d_out, int out_size, void* d_ws, size_t ws_size,
                              hipStream_t stream) {
    const float* in = (const float*)d_in[0];
    const int* tg = (const int*)d_in[1];
    float* out = (float*)d_out;
    float* lse = (float*)d_ws;                 // B*T floats
    float* ll2 = lse + (size_t)BB * TT;        // B floats
    float* lossb = ll2 + BB;                   // B floats

    hipLaunchKernelGGL(fused_kernel, dim3(BB + LSE_BLOCKS), dim3(512), 0, stream,
                       in, tg, lse, ll2);
    hipLaunchKernelGGL(bsum_kernel, dim3(BB), dim3(256), 0, stream, lse, ll2, lossb);
    hipLaunchKernelGGL(final_kernel, dim3(1), dim3(64), 0, stream, lossb, out);
}

// Round 14
// 264.218 us; speedup vs baseline: 1.1037x; 1.1037x over previous
//
#include <hip/hip_runtime.h>
#include <stdint.h>

#define BB 128
#define TT 3000
#define CC 64
#define LL 128
// S = 2L+1 = 257 ; states 0..255 on 4 waves x 64 lanes; state 256 via tail pass
#define NEGf (-1e30f)
#define LOG2E 1.4426950408889634f
#define LN2f 0.6931471805599453f
#define F 12                  // frames per ring chunk; 3000 = 250 * 12
#define NCH 250
#define NBUF 5                // ring depth: producers write c+1, wave3 reads c-3
#define NPH (NCH + 3)
#define LSE_BLOCKS 512

typedef float f32x2 __attribute__((ext_vector_type(2)));
typedef float f32x4 __attribute__((ext_vector_type(4)));

__device__ __forceinline__ float fexp2(float x){ return __builtin_amdgcn_exp2f(x); }
__device__ __forceinline__ float flog2(float x){ return __builtin_amdgcn_logf(x); }
// lane l <- lane l-1 (lane 0 -> NEG) via DPP wave_shr:1
__device__ __forceinline__ float shr1_neg(float x){
    int r = __builtin_amdgcn_update_dpp(__float_as_int(NEGf), __float_as_int(x),
                                        0x138, 0xF, 0xF, false);
    return __int_as_float(r);
}
#define DPPMAXT(x,c) fmaxf((x),__int_as_float(__builtin_amdgcn_update_dpp(0,__float_as_int(x),(c),0xF,0xF,true)))
#define DPPADDT(x,c) ((x)+__int_as_float(__builtin_amdgcn_update_dpp(0,__float_as_int(x),(c),0xF,0xF,true)))
#define RED64(OP,x) { x=OP(x,0x111); x=OP(x,0x112); x=OP(x,0x114); x=OP(x,0x118); x=OP(x,0x142); x=OP(x,0x143); }

// Fused kernel, 512 threads/block.
// Scan blocks: waves 0-3 = consumers (1 CTC state/lane, poly-log lse3; wave w
// lags w chunks; boundary batched: 3x ds_read_b128 at phase start, hist[] regs
// written once per chunk by lane63). Waves 4-7 = producers, T14-split: loads
// for chunk c+2 issued in phase c, LDS stores in phase c+1 (barrier pins them).
__global__ __launch_bounds__(512) void fused_kernel(const float* __restrict__ in,
                                                    const int* __restrict__ tgt,
                                                    float* __restrict__ lse,
                                                    float* __restrict__ ll2){
    __shared__ float emR[NBUF][F][132];  // per frame: [0..127]=em(target i), [128]=em blank
    __shared__ __align__(16) float bndR[4][3][F]; // region w read by wave w, written by w-1
    __shared__ float laL[3008];          // la255(t) (wave3 lane63)
    __shared__ float lbL[3008];          // lemB(t) (producers)
    if (blockIdx.x < BB) {
        const int b = blockIdx.x;
        const int wave = threadIdx.x >> 6;
        const int lane = threadIdx.x & 63;
        const float* fb = in + (size_t)b * TT * CC;
        const uint32_t em_base  = (uint32_t)(uintptr_t)&emR[0][0][0];
        const uint32_t bnd_base = (uint32_t)(uintptr_t)&bndR[0][0][0];

        if (wave < 4) {
            const int w = wave;
            __builtin_amdgcn_s_setprio(1);
            if (w == 0) {
                if (lane < 36) (&bndR[0][0][0])[lane] = NEGf;   // region 0 = const NEG
                if (lane >= 1 && lane <= 3) bndR[lane][0][0] = NEGf; // a(-1), chunk0 step0
                if (lane < 8) { laL[3000+lane] = NEGf; lbL[3000+lane] = 0.f; }
            }
            const bool odd = (lane & 1);
            const uint32_t em_off = odd ? (uint32_t)(32*w + (lane>>1))*4u : 512u;
            float aa = (w==0 && lane==0) ? 0.f : NEGf;   // virtual pre-t=0 state
            __syncthreads();
            for (int ph = 0; ph < NPH; ++ph) {
                const int x = ph - w;
                if (x >= 0 && x < NCH) {
                    const uint32_t buf = (uint32_t)(x % NBUF);
                    const uint32_t ra  = em_base + buf*(F*132u*4u) + em_off;
                    const uint32_t xm3 = (uint32_t)(x % 3);
                    const uint32_t xp3 = (uint32_t)((x+1) % 3);
                    const uint32_t rb  = bnd_base + (uint32_t)w*144u + xm3*48u;
                    f32x4 B4a, B4b, B4c; float ef[F]; float hist[F];
                    asm volatile("ds_read_b128 %0, %1 offset:0"  : "=v"(B4a) : "v"(rb));
                    asm volatile("ds_read_b128 %0, %1 offset:16" : "=v"(B4b) : "v"(rb));
                    asm volatile("ds_read_b128 %0, %1 offset:32" : "=v"(B4c) : "v"(rb));
                    asm volatile("ds_read_b32 %0, %1 offset:0"    : "=v"(ef[0]) : "v"(ra));
                    asm volatile("ds_read_b32 %0, %1 offset:528"  : "=v"(ef[1]) : "v"(ra));
                    asm volatile("ds_read_b32 %0, %1 offset:1056" : "=v"(ef[2]) : "v"(ra));
                    #pragma unroll
                    for (int j = 0; j < F; ++j) {
                        if (j + 3 < F)
                            asm volatile("ds_read_b32 %0, %1 offset:%2"
                                         : "=v"(ef[j+3]) : "v"(ra), "n"((j+3)*528));
                        if (j < F-3)       asm volatile("s_waitcnt lgkmcnt(3)" ::: "memory");
                        else if (j == F-3) asm volatile("s_waitcnt lgkmcnt(2)" ::: "memory");
                        else if (j == F-2) asm volatile("s_waitcnt lgkmcnt(1)" ::: "memory");
                        else               asm volatile("s_waitcnt lgkmcnt(0)" ::: "memory");
                        __builtin_amdgcn_sched_barrier(0);   // rule #18
                        float bj = (j < 4) ? B4a[j & 3] : ((j < 8) ? B4b[j & 3] : B4c[j & 3]);
                        float p1 = shr1_neg(aa);             // a_{s-1}(t-1)
                        float p2 = shr1_neg(p1);             // a_{s-2}(t-1)
                        p1 = (lane==0) ? bj : p1;            // cross-wave boundary
                        p2 = (lane==1) ? bj : p2;
                        float z = odd ? p2 : NEGf;           // skip only for odd states
                        float mx = fmaxf(fmaxf(aa,p1),z);
                        float md = __builtin_amdgcn_fmed3f(aa,p1,z);
                        float mn = fminf(fminf(aa,p1),z);
                        float e  = fexp2(md-mx) + fexp2(mn-mx);
                        float v  = __builtin_fmaf(e,0.5f,-0.5f);   // (e-1)/2 in [-.5,.5]
                        float h  = __builtin_fmaf(v,0.2f,-0.25f);  // deg-5 ln(1+v)
                        h = __builtin_fmaf(v,h,0.33333333f);
                        h = __builtin_fmaf(v,h,-0.5f);
                        h = __builtin_fmaf(v,h,1.0f);
                        aa = __builtin_fmaf(v*h, LOG2E, mx+1.0f) + ef[j];
                        hist[j] = aa;
                    }
                    // batched hand-off writes, once per chunk, lane63 only
                    if (w < 3 && lane == 63) {
                        float* reg = &bndR[w+1][0][0];
                        #pragma unroll
                        for (int j = 0; j < F-1; ++j) reg[xm3*F + j + 1] = hist[j];
                        reg[xp3*F + 0] = hist[F-1];
                    }
                    if (w == 3 && lane == 63) {
                        #pragma unroll
                        for (int j = 0; j < F; ++j) laL[x*F + j] = hist[j];
                    }
                    asm volatile("s_waitcnt lgkmcnt(0)" ::: "memory");
                }
                __syncthreads();
            }
            __syncthreads();   // tail barrier (all waves)
            if (w == 0) {
                // la256(T-1) = lse_{tau<=T-2}( la255(tau) + CBtot - CB(tau) )
                const int base = lane*47;               // 3008 = 64*47
                float seg = 0.f;
                for (int k = 0; k < 47; ++k) seg += lbL[base+k];
                float inc = seg;
                #pragma unroll
                for (int d = 1; d < 64; d <<= 1) {
                    float t = __shfl_up(inc, d, 64);
                    if (lane >= d) inc += t;
                }
                float CBtot = __int_as_float(__builtin_amdgcn_readlane(__float_as_int(inc), 63));
                float ex = inc - seg;
                float cb = ex, gm = NEGf;
                for (int k = 0; k < 47; ++k) {
                    int idx = base+k;
                    cb += lbL[idx];
                    float g = laL[idx] + (CBtot - cb);
                    g = (idx == 2999) ? NEGf : g;
                    gm = fmaxf(gm, g);
                }
                RED64(DPPMAXT, gm);
                float gmax = __int_as_float(__builtin_amdgcn_readlane(__float_as_int(gm), 63));
                cb = ex; float se = 0.f;
                for (int k = 0; k < 47; ++k) {
                    int idx = base+k;
                    cb += lbL[idx];
                    float g = laL[idx] + (CBtot - cb);
                    g = (idx == 2999) ? NEGf : g;
                    se += fexp2(g - gmax);
                }
                RED64(DPPADDT, se);
                float S = __int_as_float(__builtin_amdgcn_readlane(__float_as_int(se), 63));
                float la256 = gmax + flog2(S);
                float la255f = laL[2999];
                float m = fmaxf(la255f, la256);
                float r = m + flog2(1.0f + fexp2(-fabsf(la255f - la256)));
                if (lane == 0) ll2[b] = r;
            }
        } else {
            // producers: wave p handles frames 3p..3p+2; split load/store phases
            const int p = wave - 4;
            const int t0 = tgt[b*LL + 2*lane];       // channel for em slot 2*lane
            const int t1 = tgt[b*LL + 2*lane + 1];   // channel for em slot 2*lane+1
            float v0[3], v1[3], vb[3];
            auto loadc = [&](int cc) {
                const float* cbase = fb + (size_t)cc * F * CC;
                #pragma unroll
                for (int k = 0; k < 3; ++k) {
                    const float* fr = cbase + (3*p + k)*CC;
                    v0[k] = fr[t0]; v1[k] = fr[t1]; vb[k] = fr[63];
                }
            };
            auto storec = [&](int cc) {
                const int buf = cc % NBUF;
                #pragma unroll
                for (int k = 0; k < 3; ++k) {
                    const int f = 3*p + k;
                    f32x2 wv; wv.x = v0[k]*LOG2E; wv.y = v1[k]*LOG2E;
                    *(f32x2*)&emR[buf][f][2*lane] = wv;
                    if (lane == 0) {
                        float xb = vb[k]*LOG2E;
                        emR[buf][f][128] = xb;
                        lbL[cc*F + f] = xb;
                    }
                }
            };
            loadc(0); storec(0); loadc(1);
            __syncthreads();
            for (int ph = 0; ph < NPH; ++ph) {
                if (ph + 1 < NCH) storec(ph + 1);   // store data loaded last phase
                if (ph + 2 < NCH) loadc(ph + 2);    // issue next loads (barrier pins)
                __syncthreads();
            }
            __syncthreads();   // tail barrier
        }
        return;
    }
    // ---- softmax normalizer: one wave per (b,t) row, grid-strided ----
    int wv = (blockIdx.x - BB) * 8 + (threadIdx.x >> 6);
    int lane = threadIdx.x & 63;
    const int stride = LSE_BLOCKS * 8;
    for (int row = wv; row < BB * TT; row += stride) {
        float x = in[(size_t)row * CC + lane];
        float m = x;
        #pragma unroll
        for (int d = 32; d >= 1; d >>= 1) m = fmaxf(m, __shfl_xor(m, d, 64));
        float s = fexp2((x - m) * LOG2E);
        #pragma unroll
        for (int d = 32; d >= 1; d >>= 1) s += __shfl_xor(s, d, 64);
        if (lane == 0) lse[row] = m + flog2(s) * LN2f;
    }
}

// per-batch loss_b = sum_t lse_nat[b,t] - ll2[b]*ln2
__global__ __launch_bounds__(256) void bsum_kernel(const float* __restrict__ lse,
                                                   const float* __restrict__ ll2,
                                                   float* __restrict__ lossb) {
    __shared__ float red[256];
    int b = blockIdx.x;
    float s = 0.f;
    for (int i = threadIdx.x; i < TT; i += 256) s += lse[(size_t)b * TT + i];
    red[threadIdx.x] = s;
    __syncthreads();
    #pragma unroll
    for (int w = 128; w >= 1; w >>= 1) {
        if (threadIdx.x < w) red[threadIdx.x] += red[threadIdx.x + w];
        __syncthreads();
    }
    if (threadIdx.x == 0) lossb[b] = red[0] - ll2[b] * LN2f;
}

// mean over batch
__global__ __launch_bounds__(64) void final_kernel(const float* __restrict__ lossb,
                                                   float* __restrict__ out) {
    int lane = threadIdx.x;
    float v = lossb[lane] + lossb[lane + 64];
    #pragma unroll
    for (int d = 32; d >= 1; d >>= 1) v += __shfl_xor(v, d, 64);
    if (lane == 0) out[0] = v / (float)BB;
}

extern "C" void kernel_launch(void* const* d_in, const int* in_sizes, int n_in,
                              void* d_out, int out_size, void* d_ws, size_t ws_size,
                              hipStream_t stream) {
    const float* in = (const float*)d_in[0];
    const int* tg = (const int*)d_in[1];
    float* out = (float*)d_out;
    float* lse = (float*)d_ws;                 // B*T floats
    float* ll2 = lse + (size_t)BB * TT;        // B floats
    float* lossb = ll2 + BB;                   // B floats

    hipLaunchKernelGGL(fused_kernel, dim3(BB + LSE_BLOCKS), dim3(512), 0, stream,
                       in, tg, lse, ll2);
    hipLaunchKernelGGL(bsum_kernel, dim3(BB), dim3(256), 0, stream, lse, ll2, lossb);
    hipLaunchKernelGGL(final_kernel, dim3(1), dim3(64), 0, stream, lossb, out);
}